// Round 1
// baseline (996.592 us; speedup 1.0000x reference)
//
#include <hip/hip_runtime.h>

#define NIN 784
#define BANKS 64
#define NLAYER 15
#define FAN 8
#define DD 10
#define NBF (BANKS*DD)      // 640 features per sample per layer
#define SAMP 8              // samples per block in layer kernel

// ---------------- Kernel A: input GEMM ----------------
// acts[b][n] = relu( sum_i x[b][i]*Wi[n][i] + bi[n] ),  n = bank*10+o
#define BM 128
#define BN 64
#define BK 16

__global__ __launch_bounds__(256)
void input_gemm(const float* __restrict__ x, const float* __restrict__ Wi,
                const float* __restrict__ bi, float* __restrict__ acts)
{
    __shared__ float As[BK][BM + 4];
    __shared__ float Bs[BK][BN + 4];
    const int tid = threadIdx.x;
    const int tx = tid & 15, ty = tid >> 4;
    const int m0 = blockIdx.x * BM;
    const int n0 = blockIdx.y * BN;

    float acc[8][4];
#pragma unroll
    for (int i = 0; i < 8; ++i)
#pragma unroll
        for (int j = 0; j < 4; ++j) acc[i][j] = 0.f;

    for (int kb = 0; kb < NIN / BK; ++kb) {
        // load A tile (128 x 16)
#pragma unroll
        for (int i = 0; i < 2; ++i) {
            int flat = tid + 256 * i;
            int m = flat >> 2, kq = flat & 3;
            float4 v = *(const float4*)(x + (m0 + m) * NIN + kb * BK + kq * 4);
            As[kq*4+0][m] = v.x; As[kq*4+1][m] = v.y;
            As[kq*4+2][m] = v.z; As[kq*4+3][m] = v.w;
        }
        // load B tile (64 x 16)
        {
            int n = tid >> 2, kq = tid & 3;
            float4 v = *(const float4*)(Wi + (n0 + n) * NIN + kb * BK + kq * 4);
            Bs[kq*4+0][n] = v.x; Bs[kq*4+1][n] = v.y;
            Bs[kq*4+2][n] = v.z; Bs[kq*4+3][n] = v.w;
        }
        __syncthreads();
#pragma unroll
        for (int k = 0; k < BK; ++k) {
            float4 a0 = *(const float4*)(&As[k][ty*8]);
            float4 a1 = *(const float4*)(&As[k][ty*8+4]);
            float4 bb = *(const float4*)(&Bs[k][tx*4]);
            float av[8] = {a0.x,a0.y,a0.z,a0.w,a1.x,a1.y,a1.z,a1.w};
            float bv[4] = {bb.x,bb.y,bb.z,bb.w};
#pragma unroll
            for (int i = 0; i < 8; ++i)
#pragma unroll
                for (int j = 0; j < 4; ++j)
                    acc[i][j] = fmaf(av[i], bv[j], acc[i][j]);
        }
        __syncthreads();
    }
    float4 bv = *(const float4*)(bi + n0 + tx*4);
#pragma unroll
    for (int i = 0; i < 8; ++i) {
        int row = m0 + ty*8 + i;
        float4 o;
        o.x = fmaxf(acc[i][0] + bv.x, 0.f);
        o.y = fmaxf(acc[i][1] + bv.y, 0.f);
        o.z = fmaxf(acc[i][2] + bv.z, 0.f);
        o.w = fmaxf(acc[i][3] + bv.w, 0.f);
        *(float4*)(acts + row * NBF + n0 + tx*4) = o;
    }
}

// ---------------- Kernel B: 15 routing layers + epilogue ----------------
// One block = SAMP samples; acts double-buffered in LDS; gates in LDS.
// Layer l:
//   gate[b,s,k] = clip(dot(acts[b,s,:], Wg[l,s,k,:]) + bg[l,s,k], 0, 1)
//   newacts[b,t,e] = relu( sum_{k=0..7, s=(t-k)&63} gate[b,s,k] *
//                          dot(acts[b,s,:], Wd[l,s,k,e,:]) )
__global__ __launch_bounds__(256)
void routenet_layers(const float* __restrict__ acts0,
                     const float* __restrict__ x, const float* __restrict__ Wi,
                     const float* __restrict__ bi,
                     const float* __restrict__ Wg, const float* __restrict__ bg,
                     const float* __restrict__ Wd, const float* __restrict__ Wo,
                     float* __restrict__ out, unsigned int* __restrict__ nopen_g)
{
    // layout: [acts0 20480B][acts1 20480B][gates 16384B]
    __shared__ __align__(16) char smem[57344];
    float* buf0  = (float*)smem;             // SAMP*640
    float* buf1  = (float*)(smem + 20480);   // SAMP*640
    float* gatem = (float*)(smem + 40960);   // SAMP*512
    __shared__ float gsumAcc[SAMP];
    __shared__ unsigned int nopenAcc;

    const int tid = threadIdx.x;
    const int b0  = blockIdx.x * SAMP;

    if (tid < SAMP) gsumAcc[tid] = 0.f;
    if (tid == 0)   nopenAcc = 0;

    float* ac = buf0;
    float* an = buf1;

    if (acts0) {
        const float4* src = (const float4*)(acts0 + (size_t)b0 * NBF);
        float4* dst = (float4*)ac;
#pragma unroll
        for (int i = 0; i < 5; ++i) dst[tid + 256*i] = src[tid + 256*i];
    } else {
        // fallback: compute input layer here (ws too small for acts buffer)
        float* xs = an;  // overlays buf1 + start of gates: 6272 floats, fits
        const float4* src = (const float4*)(x + (size_t)b0 * NIN);
        float4* dst = (float4*)xs;
        for (int i = 0; i < 7; ++i) {
            int idx = tid + 256*i;
            if (idx < (SAMP*NIN)/4) dst[idx] = src[idx];
        }
        __syncthreads();
        for (int it = 0; it < 3; ++it) {
            int n = tid + 256*it;
            if (n < NBF) {
                float accv[SAMP];
#pragma unroll
                for (int b = 0; b < SAMP; ++b) accv[b] = bi[n];
                const float4* wrow = (const float4*)(Wi + (size_t)n * NIN);
                for (int i4 = 0; i4 < NIN/4; ++i4) {
                    float4 w = wrow[i4];
#pragma unroll
                    for (int b = 0; b < SAMP; ++b) {
                        const float* xb = xs + b*NIN + i4*4;
                        accv[b] = fmaf(xb[0], w.x, accv[b]);
                        accv[b] = fmaf(xb[1], w.y, accv[b]);
                        accv[b] = fmaf(xb[2], w.z, accv[b]);
                        accv[b] = fmaf(xb[3], w.w, accv[b]);
                    }
                }
#pragma unroll
                for (int b = 0; b < SAMP; ++b)
                    ac[b*NBF + n] = fmaxf(accv[b], 0.f);
            }
        }
    }
    __syncthreads();

    for (int l = 0; l < NLAYER; ++l) {
        const float* Wg_l = Wg + (size_t)l * BANKS*FAN*DD;   // 5120
        const float* bg_l = bg + (size_t)l * BANKS*FAN;      // 512
        const float* Wd_l = Wd + (size_t)l * BANKS*FAN*DD*DD; // 51200

        // phase 1: gates (SAMP*512 items, 16 per thread)
        float gsl[SAMP];
#pragma unroll
        for (int b = 0; b < SAMP; ++b) gsl[b] = 0.f;
        unsigned int nop = 0;
#pragma unroll
        for (int i = 0; i < 16; ++i) {
            const int b = i >> 1;               // compile-time
            int e = (tid + 256*i) & 511;        // s*8+k
            int s = e >> 3;
            float z = bg_l[e];
            const float2* wp = (const float2*)(Wg_l + e*DD);
            const float2* ap = (const float2*)(ac + b*NBF + s*DD);
#pragma unroll
            for (int d2 = 0; d2 < 5; ++d2) {
                float2 w = wp[d2], a = ap[d2];
                z = fmaf(a.x, w.x, z);
                z = fmaf(a.y, w.y, z);
            }
            float gate = fminf(fmaxf(z, 0.f), 1.f);
            gatem[b*512 + e] = gate;
            gsl[b] += gate;
            nop += (z > 0.f) ? 1u : 0u;
        }
        // reduce gate sums (per sample) and open count
#pragma unroll
        for (int b = 0; b < SAMP; ++b) {
            float v = gsl[b];
#pragma unroll
            for (int off = 32; off; off >>= 1) v += __shfl_xor(v, off);
            if ((tid & 63) == 0) atomicAdd(&gsumAcc[b], v);
        }
        {
            unsigned int v = nop;
#pragma unroll
            for (int off = 32; off; off >>= 1) v += __shfl_xor(v, off);
            if ((tid & 63) == 0) atomicAdd(&nopenAcc, v);
        }
        __syncthreads();

        // phase 2: data + gated scatter (SAMP*640 items, 20 per thread)
        for (int j = 0; j < 20; ++j) {
            unsigned item = (unsigned)tid + 256u*j;
            unsigned b = item / 640u;
            unsigned r = item - b*640u;
            unsigned t = r / 10u;
            unsigned e = r - t*10u;
            const float* acb = ac + b*NBF;
            float acc = 0.f;
#pragma unroll
            for (int k = 0; k < FAN; ++k) {
                unsigned s = (t - k) & 63u;
                float gk = gatem[b*512 + s*8 + k];
                const float2* wp = (const float2*)(Wd_l + (s*80u + k*10u + e)*10u);
                const float2* ap = (const float2*)(acb + s*DD);
                float dot = 0.f;
#pragma unroll
                for (int d2 = 0; d2 < 5; ++d2) {
                    float2 w = wp[d2], a = ap[d2];
                    dot = fmaf(a.x, w.x, dot);
                    dot = fmaf(a.y, w.y, dot);
                }
                acc = fmaf(gk, dot, acc);
            }
            an[b*NBF + t*DD + e] = fmaxf(acc, 0.f);
        }
        { float* tmp = ac; ac = an; an = tmp; }
        __syncthreads();
    }

    // epilogue: output projection, per-sample gate activity
#pragma unroll
    for (int j = 0; j < 2; ++j) {
        int item = tid + 256*j;            // 0..511
        int b = item >> 6;
        int t = item & 63;
        const float2* ap = (const float2*)(ac + b*NBF + t*DD);
        const float2* wp = (const float2*)(Wo + t*DD);
        float v = 0.f;
#pragma unroll
        for (int d2 = 0; d2 < 5; ++d2) {
            float2 w = wp[d2], a = ap[d2];
            v = fmaf(a.x, w.x, v);
            v = fmaf(a.y, w.y, v);
        }
        out[(size_t)(b0 + b)*BANKS + t] = fmaxf(v, 0.f);
    }
    if (tid < SAMP)
        out[(size_t)4096*BANKS + b0 + tid] = gsumAcc[tid] * (1.0f/7680.0f);
    if (tid == 0)
        atomicAdd(nopen_g, nopenAcc);
}

// ---------------- Kernel C: finalize scalar ----------------
__global__ void finalize_prob(const unsigned int* __restrict__ nopen,
                              float* __restrict__ out)
{
    out[4096*64 + 4096] = (float)(*nopen) / 31457280.0f;  // /(7680*4096)
}

extern "C" void kernel_launch(void* const* d_in, const int* in_sizes, int n_in,
                              void* d_out, int out_size, void* d_ws, size_t ws_size,
                              hipStream_t stream)
{
    const float* x  = (const float*)d_in[0];
    const float* Wi = (const float*)d_in[1];
    const float* bi = (const float*)d_in[2];
    const float* Wg = (const float*)d_in[3];
    const float* bg = (const float*)d_in[4];
    const float* Wd = (const float*)d_in[5];
    const float* Wo = (const float*)d_in[6];
    float* out = (float*)d_out;

    const size_t ACTS_BYTES = (size_t)4096 * NBF * 4;   // 10.5 MB
    bool use_ws = ws_size >= ACTS_BYTES + 64;

    float* acts0 = use_ws ? (float*)d_ws : nullptr;
    unsigned int* nopen = use_ws
        ? (unsigned int*)((char*)d_ws + ACTS_BYTES)
        : (unsigned int*)d_ws;

    hipMemsetAsync(nopen, 0, 4, stream);

    if (use_ws) {
        dim3 grid(4096 / BM, NBF / BN);
        input_gemm<<<grid, 256, 0, stream>>>(x, Wi, bi, acts0);
    }
    routenet_layers<<<4096 / SAMP, 256, 0, stream>>>(
        acts0, x, Wi, bi, Wg, bg, Wd, Wo, out, nopen);
    finalize_prob<<<1, 1, 0, stream>>>(nopen, out);
}

// Round 2
// 583.678 us; speedup vs baseline: 1.7074x; 1.7074x over previous
//
#include <hip/hip_runtime.h>

#define NIN 784
#define BANKS 64
#define NLAYER 15
#define FAN 8
#define DD 10
#define NBF (BANKS*DD)      // 640
#define NS 4                // samples per lane in the wave kernel

// ---------------- Kernel A: input GEMM ----------------
#define BM 128
#define BN 64
#define BK 16

__global__ __launch_bounds__(256)
void input_gemm(const float* __restrict__ x, const float* __restrict__ Wi,
                const float* __restrict__ bi, float* __restrict__ acts)
{
    __shared__ float As[BK][BM + 4];
    __shared__ float Bs[BK][BN + 4];
    const int tid = threadIdx.x;
    const int tx = tid & 15, ty = tid >> 4;
    const int m0 = blockIdx.x * BM;
    const int n0 = blockIdx.y * BN;

    float acc[8][4];
#pragma unroll
    for (int i = 0; i < 8; ++i)
#pragma unroll
        for (int j = 0; j < 4; ++j) acc[i][j] = 0.f;

    for (int kb = 0; kb < NIN / BK; ++kb) {
#pragma unroll
        for (int i = 0; i < 2; ++i) {
            int flat = tid + 256 * i;
            int m = flat >> 2, kq = flat & 3;
            float4 v = *(const float4*)(x + (m0 + m) * NIN + kb * BK + kq * 4);
            As[kq*4+0][m] = v.x; As[kq*4+1][m] = v.y;
            As[kq*4+2][m] = v.z; As[kq*4+3][m] = v.w;
        }
        {
            int n = tid >> 2, kq = tid & 3;
            float4 v = *(const float4*)(Wi + (n0 + n) * NIN + kb * BK + kq * 4);
            Bs[kq*4+0][n] = v.x; Bs[kq*4+1][n] = v.y;
            Bs[kq*4+2][n] = v.z; Bs[kq*4+3][n] = v.w;
        }
        __syncthreads();
#pragma unroll
        for (int k = 0; k < BK; ++k) {
            float4 a0 = *(const float4*)(&As[k][ty*8]);
            float4 a1 = *(const float4*)(&As[k][ty*8+4]);
            float4 bb = *(const float4*)(&Bs[k][tx*4]);
            float av[8] = {a0.x,a0.y,a0.z,a0.w,a1.x,a1.y,a1.z,a1.w};
            float bv[4] = {bb.x,bb.y,bb.z,bb.w};
#pragma unroll
            for (int i = 0; i < 8; ++i)
#pragma unroll
                for (int j = 0; j < 4; ++j)
                    acc[i][j] = fmaf(av[i], bv[j], acc[i][j]);
        }
        __syncthreads();
    }
    float4 bv = *(const float4*)(bi + n0 + tx*4);
#pragma unroll
    for (int i = 0; i < 8; ++i) {
        int row = m0 + ty*8 + i;
        float4 o;
        o.x = fmaxf(acc[i][0] + bv.x, 0.f);
        o.y = fmaxf(acc[i][1] + bv.y, 0.f);
        o.z = fmaxf(acc[i][2] + bv.z, 0.f);
        o.w = fmaxf(acc[i][3] + bv.w, 0.f);
        *(float4*)(acts + row * NBF + n0 + tx*4) = o;
    }
}

// compile-time float4 component select (keeps arrays in registers)
__device__ __forceinline__ float f4c(const float4& v, int c) {
    return c == 0 ? v.x : (c == 1 ? v.y : (c == 2 ? v.z : v.w));
}

// ---------------- Kernel B: wave-per-4-samples, lane = bank ----------------
// acts live in registers (lane t holds bank t, NS samples x 10 dims).
// Per layer, per k: lane s computes its own gate and data contribution to
// target (s+k)%64, rotates it across the wave with __shfl, accumulates.
// No LDS, no barriers.
__global__ __launch_bounds__(64, 1)
void routenet_waves(const float* __restrict__ acts0,
                    const float* __restrict__ x, const float* __restrict__ Wi,
                    const float* __restrict__ bi,
                    const float* __restrict__ Wg, const float* __restrict__ bg,
                    const float* __restrict__ Wd, const float* __restrict__ Wo,
                    float* __restrict__ out, unsigned int* __restrict__ nopen_g)
{
    const int lane = threadIdx.x;          // bank index (0..63)
    const int b0 = blockIdx.x * NS;        // first sample of this wave

    float a[NS][DD];

    if (acts0) {
#pragma unroll
        for (int s = 0; s < NS; ++s) {
            const float2* p = (const float2*)(acts0 + (size_t)(b0 + s) * NBF + lane * DD);
#pragma unroll
            for (int d2 = 0; d2 < 5; ++d2) {
                float2 v = p[d2];
                a[s][d2*2]   = v.x;
                a[s][d2*2+1] = v.y;
            }
        }
    } else {
        // slow fallback: compute input layer directly
        for (int s = 0; s < NS; ++s) {
            const float* xb = x + (size_t)(b0 + s) * NIN;
            for (int d = 0; d < DD; ++d) {
                int n = lane * DD + d;
                const float* wr = Wi + (size_t)n * NIN;
                float z = bi[n];
                for (int i = 0; i < NIN; ++i) z = fmaf(xb[i], wr[i], z);
                a[s][d] = fmaxf(z, 0.f);
            }
        }
    }

    float gsum[NS];
#pragma unroll
    for (int s = 0; s < NS; ++s) gsum[s] = 0.f;
    unsigned int nop = 0;

    for (int l = 0; l < NLAYER; ++l) {
        const float* Wg_l = Wg + (size_t)l * BANKS*FAN*DD + lane * (FAN*DD);   // [8][10]
        const float* bg_l = bg + (size_t)l * BANKS*FAN + lane * FAN;           // [8]
        const float* Wd_l = Wd + (size_t)l * BANKS*FAN*DD*DD + lane * (FAN*DD*DD); // [8][10][10]

        float acc[NS][DD];
#pragma unroll
        for (int s = 0; s < NS; ++s)
#pragma unroll
            for (int d = 0; d < DD; ++d) acc[s][d] = 0.f;

#pragma unroll 2
        for (int k = 0; k < FAN; ++k) {
            // load this lane's 10x10 Wd block as 25 float4 (16B-aligned: 400B blocks)
            float4 wv[25];
            const float4* wp = (const float4*)(Wd_l + k * (DD*DD));
#pragma unroll
            for (int i = 0; i < 25; ++i) wv[i] = wp[i];

            // gate weights: 10 floats
            float wg[DD];
            {
                const float2* gp = (const float2*)(Wg_l + k * DD);
#pragma unroll
                for (int d2 = 0; d2 < 5; ++d2) {
                    float2 v = gp[d2];
                    wg[d2*2] = v.x; wg[d2*2+1] = v.y;
                }
            }
            float bgv = bg_l[k];

            float gz[NS];
#pragma unroll
            for (int s = 0; s < NS; ++s) {
                float z = bgv;
#pragma unroll
                for (int d = 0; d < DD; ++d) z = fmaf(a[s][d], wg[d], z);
                float gate = fminf(fmaxf(z, 0.f), 1.f);
                gsum[s] += gate;
                nop += (z > 0.f) ? 1u : 0u;
                gz[s] = gate;
            }

            // data: c[s][e] = gate * dot(a[s], Wd[k][e][:]); rotate by k; accumulate
            const int src = (lane - k) & 63;
#pragma unroll
            for (int e = 0; e < DD; ++e) {
#pragma unroll
                for (int s = 0; s < NS; ++s) {
                    float dot = 0.f;
#pragma unroll
                    for (int d = 0; d < DD; ++d) {
                        const int flat = e * DD + d;
                        dot = fmaf(a[s][d], f4c(wv[flat >> 2], flat & 3), dot);
                    }
                    float c = gz[s] * dot;
                    acc[s][e] += __shfl(c, src, 64);
                }
            }
        }

#pragma unroll
        for (int s = 0; s < NS; ++s)
#pragma unroll
            for (int d = 0; d < DD; ++d) a[s][d] = fmaxf(acc[s][d], 0.f);
    }

    // output projection: out[b, lane] = relu(dot(a[b], Wo[lane]))
    {
        float wo[DD];
        const float2* p = (const float2*)(Wo + lane * DD);
#pragma unroll
        for (int d2 = 0; d2 < 5; ++d2) {
            float2 v = p[d2];
            wo[d2*2] = v.x; wo[d2*2+1] = v.y;
        }
#pragma unroll
        for (int s = 0; s < NS; ++s) {
            float v = 0.f;
#pragma unroll
            for (int d = 0; d < DD; ++d) v = fmaf(a[s][d], wo[d], v);
            out[(size_t)(b0 + s) * BANKS + lane] = fmaxf(v, 0.f);
        }
    }

    // gate stats: reduce across the wave's 64 lanes
#pragma unroll
    for (int s = 0; s < NS; ++s) {
        float v = gsum[s];
#pragma unroll
        for (int off = 32; off; off >>= 1) v += __shfl_xor(v, off, 64);
        if (lane == 0)
            out[(size_t)4096 * BANKS + b0 + s] = v * (1.0f / 7680.0f);
    }
    {
        unsigned int v = nop;
#pragma unroll
        for (int off = 32; off; off >>= 1) v += __shfl_xor(v, off, 64);
        if (lane == 0) atomicAdd(nopen_g, v);
    }
}

// ---------------- Kernel C: finalize scalar ----------------
__global__ void finalize_prob(const unsigned int* __restrict__ nopen,
                              float* __restrict__ out)
{
    out[4096*64 + 4096] = (float)(*nopen) / 31457280.0f;  // /(7680*4096)
}

extern "C" void kernel_launch(void* const* d_in, const int* in_sizes, int n_in,
                              void* d_out, int out_size, void* d_ws, size_t ws_size,
                              hipStream_t stream)
{
    const float* x  = (const float*)d_in[0];
    const float* Wi = (const float*)d_in[1];
    const float* bi = (const float*)d_in[2];
    const float* Wg = (const float*)d_in[3];
    const float* bg = (const float*)d_in[4];
    const float* Wd = (const float*)d_in[5];
    const float* Wo = (const float*)d_in[6];
    float* out = (float*)d_out;

    const size_t ACTS_BYTES = (size_t)4096 * NBF * 4;   // 10.5 MB
    bool use_ws = ws_size >= ACTS_BYTES + 64;

    float* acts0 = use_ws ? (float*)d_ws : nullptr;
    unsigned int* nopen = use_ws
        ? (unsigned int*)((char*)d_ws + ACTS_BYTES)
        : (unsigned int*)d_ws;

    hipMemsetAsync(nopen, 0, 4, stream);

    if (use_ws) {
        dim3 grid(4096 / BM, NBF / BN);
        input_gemm<<<grid, 256, 0, stream>>>(x, Wi, bi, acts0);
    }
    routenet_waves<<<4096 / NS, 64, 0, stream>>>(
        acts0, x, Wi, bi, Wg, bg, Wd, Wo, out, nopen);
    finalize_prob<<<1, 1, 0, stream>>>(nopen, out);
}

// Round 3
// 384.565 us; speedup vs baseline: 2.5915x; 1.5178x over previous
//
#include <hip/hip_runtime.h>

#define NIN 784
#define BANKS 64
#define NLAYER 15
#define FAN 8
#define DD 10
#define NBF (BANKS*DD)      // 640
#define NSW 4               // samples per wave
#define WAVES 4
#define NSB (NSW*WAVES)     // 16 samples per block

// ---------------- Kernel A: input GEMM ----------------
#define BM 128
#define BN 64
#define BK 16

__global__ __launch_bounds__(256)
void input_gemm(const float* __restrict__ x, const float* __restrict__ Wi,
                const float* __restrict__ bi, float* __restrict__ acts)
{
    __shared__ float As[BK][BM + 4];
    __shared__ float Bs[BK][BN + 4];
    const int tid = threadIdx.x;
    const int tx = tid & 15, ty = tid >> 4;
    const int m0 = blockIdx.x * BM;
    const int n0 = blockIdx.y * BN;

    float acc[8][4];
#pragma unroll
    for (int i = 0; i < 8; ++i)
#pragma unroll
        for (int j = 0; j < 4; ++j) acc[i][j] = 0.f;

    for (int kb = 0; kb < NIN / BK; ++kb) {
#pragma unroll
        for (int i = 0; i < 2; ++i) {
            int flat = tid + 256 * i;
            int m = flat >> 2, kq = flat & 3;
            float4 v = *(const float4*)(x + (m0 + m) * NIN + kb * BK + kq * 4);
            As[kq*4+0][m] = v.x; As[kq*4+1][m] = v.y;
            As[kq*4+2][m] = v.z; As[kq*4+3][m] = v.w;
        }
        {
            int n = tid >> 2, kq = tid & 3;
            float4 v = *(const float4*)(Wi + (n0 + n) * NIN + kb * BK + kq * 4);
            Bs[kq*4+0][n] = v.x; Bs[kq*4+1][n] = v.y;
            Bs[kq*4+2][n] = v.z; Bs[kq*4+3][n] = v.w;
        }
        __syncthreads();
#pragma unroll
        for (int k = 0; k < BK; ++k) {
            float4 a0 = *(const float4*)(&As[k][ty*8]);
            float4 a1 = *(const float4*)(&As[k][ty*8+4]);
            float4 bb = *(const float4*)(&Bs[k][tx*4]);
            float av[8] = {a0.x,a0.y,a0.z,a0.w,a1.x,a1.y,a1.z,a1.w};
            float bv[4] = {bb.x,bb.y,bb.z,bb.w};
#pragma unroll
            for (int i = 0; i < 8; ++i)
#pragma unroll
                for (int j = 0; j < 4; ++j)
                    acc[i][j] = fmaf(av[i], bv[j], acc[i][j]);
        }
        __syncthreads();
    }
    float4 bv = *(const float4*)(bi + n0 + tx*4);
#pragma unroll
    for (int i = 0; i < 8; ++i) {
        int row = m0 + ty*8 + i;
        float4 o;
        o.x = fmaxf(acc[i][0] + bv.x, 0.f);
        o.y = fmaxf(acc[i][1] + bv.y, 0.f);
        o.z = fmaxf(acc[i][2] + bv.z, 0.f);
        o.w = fmaxf(acc[i][3] + bv.w, 0.f);
        *(float4*)(acts + row * NBF + n0 + tx*4) = o;
    }
}

// compile-time float4 component select
__device__ __forceinline__ float f4c(const float4& v, int c) {
    return c == 0 ? v.x : (c == 1 ? v.y : (c == 2 ? v.z : v.w));
}

typedef const __attribute__((address_space(1))) void gas_void;
typedef __attribute__((address_space(3))) void las_void;

__device__ __forceinline__ void gll16(const void* g, void* l) {
    __builtin_amdgcn_global_load_lds((gas_void*)g, (las_void*)l, 16, 0, 0);
}

// ---------------- Kernel B: 4 waves x 4 samples, LDS-staged weights ----------------
// lane = bank. Wd staged per 2-k chunk into transposed [kk][quad][bank] layout
// (conflict-free ds_read_b128), double-buffered; Wg+bg staged per layer,
// double-buffered by layer parity. Counted vmcnt keeps next-chunk loads in
// flight across raw s_barriers (T3/T4 pattern).
__global__ __launch_bounds__(256, 1)
void routenet_v3(const float* __restrict__ acts0,
                 const float* __restrict__ x, const float* __restrict__ Wi,
                 const float* __restrict__ bi,
                 const float* __restrict__ Wg, const float* __restrict__ bg,
                 const float* __restrict__ Wd, const float* __restrict__ Wo,
                 float* __restrict__ out, unsigned int* __restrict__ nopen_g)
{
    __shared__ float4 wdbuf[2][2][25][64];   // [chunk parity][kk][quad][bank] 102400 B
    __shared__ float4 wgbuf[2][22][64];      // [layer parity][quad][bank]     45056 B

    const int tid  = threadIdx.x;
    const int lane = tid & 63;
    const int w    = tid >> 6;
    const int b0   = blockIdx.x * NSB + w * NSW;   // this wave's first sample

    float a[NSW][DD];

    if (acts0) {
#pragma unroll
        for (int s = 0; s < NSW; ++s) {
            const float2* p = (const float2*)(acts0 + (size_t)(b0 + s) * NBF + lane * DD);
#pragma unroll
            for (int d2 = 0; d2 < 5; ++d2) {
                float2 v = p[d2];
                a[s][d2*2]   = v.x;
                a[s][d2*2+1] = v.y;
            }
        }
    } else {
        for (int s = 0; s < NSW; ++s) {
            const float* xb = x + (size_t)(b0 + s) * NIN;
            for (int d = 0; d < DD; ++d) {
                int n = lane * DD + d;
                const float* wr = Wi + (size_t)n * NIN;
                float z = bi[n];
                for (int i = 0; i < NIN; ++i) z = fmaf(xb[i], wr[i], z);
                a[s][d] = fmaxf(z, 0.f);
            }
        }
    }

    float gsum[NSW];
#pragma unroll
    for (int s = 0; s < NSW; ++s) gsum[s] = 0.f;
    unsigned int nop = 0;

    // --- staging helpers ---
    // Wd rows: 50 per chunk (2 k x 25 quads); wave w takes rows w, w+4, ...
    auto stage_wd = [&](int l, int c, int pdst) {
        const float* base = Wd + (size_t)l * (BANKS*FAN*DD*DD) + (size_t)lane * (FAN*DD*DD);
#pragma unroll
        for (int j = 0; j < 13; ++j) {
            int r = w + 4 * j;
            if (r < 50) {
                int kk = (r >= 25) ? 1 : 0;
                int i  = r - 25 * kk;
                gll16(base + (c*2 + kk) * (DD*DD) + i * 4, &wdbuf[pdst][kk][i][0]);
            }
        }
    };
    // Wg rows: quads 0..19 = Wg (80 floats/bank), 20..21 = bg (8 floats/bank)
    auto stage_wg = [&](int l) {
        const int lp = l & 1;
        const float* gbase = Wg + (size_t)l * (BANKS*FAN*DD) + lane * (FAN*DD);
        const float* bbase = bg + (size_t)l * (BANKS*FAN)   + lane * FAN;
#pragma unroll
        for (int j = 0; j < 6; ++j) {
            int r = 50 + w + 4 * j;
            if (r < 72) {
                int q = r - 50;
                if (q < 20) gll16(gbase + q * 4, &wgbuf[lp][q][0]);
                else        gll16(bbase + (q - 20) * 4, &wgbuf[lp][q][0]);
            }
        }
    };

    // prologue: stage layer 0 chunk 0 + layer 0 gate weights
    stage_wd(0, 0, 0);
    stage_wg(0);
    asm volatile("s_waitcnt vmcnt(0)" ::: "memory");
    asm volatile("s_barrier" ::: "memory");

    for (int l = 0; l < NLAYER; ++l) {
        const int lp = l & 1;

        float acc[NSW][DD];
#pragma unroll
        for (int s = 0; s < NSW; ++s)
#pragma unroll
            for (int d = 0; d < DD; ++d) acc[s][d] = 0.f;

#pragma unroll
        for (int c = 0; c < 4; ++c) {
            const int p = c & 1;

            // issue next chunk's staging into the other buffer (stays in flight
            // across the barrier — counted vmcnt, never drain to 0 mid-loop)
            if (c < 3) {
                stage_wd(l, c + 1, p ^ 1);
                asm volatile("s_waitcnt vmcnt(12)" ::: "memory");
            } else if (l + 1 < NLAYER) {
                stage_wd(l + 1, 0, p ^ 1);
                stage_wg(l + 1);
                asm volatile("s_waitcnt vmcnt(17)" ::: "memory");
            } else {
                asm volatile("s_waitcnt vmcnt(0)" ::: "memory");
            }
            asm volatile("s_barrier" ::: "memory");   // current chunk's data landed everywhere

            // compute k = 2c, 2c+1 from wdbuf[p], gates from wgbuf[lp]
#pragma unroll
            for (int kk = 0; kk < 2; ++kk) {
                const int k = 2 * c + kk;

                float wgv[DD];
#pragma unroll
                for (int d = 0; d < DD; ++d) {
                    const int fl = k * DD + d;
                    wgv[d] = f4c(wgbuf[lp][fl >> 2][lane], fl & 3);
                }
                const float bgv = f4c(wgbuf[lp][20 + (k >> 2)][lane], k & 3);

                float gz[NSW];
#pragma unroll
                for (int s = 0; s < NSW; ++s) {
                    float z = bgv;
#pragma unroll
                    for (int d = 0; d < DD; ++d) z = fmaf(a[s][d], wgv[d], z);
                    float gate = fminf(fmaxf(z, 0.f), 1.f);
                    gsum[s] += gate;
                    nop += (z > 0.f) ? 1u : 0u;
                    gz[s] = gate;
                }

                float4 wv[25];
#pragma unroll
                for (int i = 0; i < 25; ++i) wv[i] = wdbuf[p][kk][i][lane];

                const int src = (lane - k) & 63;
#pragma unroll
                for (int e = 0; e < DD; ++e) {
#pragma unroll
                    for (int s = 0; s < NSW; ++s) {
                        float dot = 0.f;
#pragma unroll
                        for (int d = 0; d < DD; ++d) {
                            const int flat = e * DD + d;
                            dot = fmaf(a[s][d], f4c(wv[flat >> 2], flat & 3), dot);
                        }
                        acc[s][e] += __shfl(gz[s] * dot, src, 64);
                    }
                }
            }

            // everyone done reading wdbuf[p] before next iteration re-stages it
            asm volatile("s_waitcnt lgkmcnt(0)" ::: "memory");
            asm volatile("s_barrier" ::: "memory");
        }

#pragma unroll
        for (int s = 0; s < NSW; ++s)
#pragma unroll
            for (int d = 0; d < DD; ++d) a[s][d] = fmaxf(acc[s][d], 0.f);
    }

    // output projection
    {
        float wo[DD];
        const float2* p = (const float2*)(Wo + lane * DD);
#pragma unroll
        for (int d2 = 0; d2 < 5; ++d2) {
            float2 v = p[d2];
            wo[d2*2] = v.x; wo[d2*2+1] = v.y;
        }
#pragma unroll
        for (int s = 0; s < NSW; ++s) {
            float v = 0.f;
#pragma unroll
            for (int d = 0; d < DD; ++d) v = fmaf(a[s][d], wo[d], v);
            out[(size_t)(b0 + s) * BANKS + lane] = fmaxf(v, 0.f);
        }
    }

    // gate stats
#pragma unroll
    for (int s = 0; s < NSW; ++s) {
        float v = gsum[s];
#pragma unroll
        for (int off = 32; off; off >>= 1) v += __shfl_xor(v, off, 64);
        if (lane == 0)
            out[(size_t)4096 * BANKS + b0 + s] = v * (1.0f / 7680.0f);
    }
    {
        unsigned int v = nop;
#pragma unroll
        for (int off = 32; off; off >>= 1) v += __shfl_xor(v, off, 64);
        if (lane == 0) atomicAdd(nopen_g, v);
    }
}

// ---------------- Kernel C: finalize scalar ----------------
__global__ void finalize_prob(const unsigned int* __restrict__ nopen,
                              float* __restrict__ out)
{
    out[4096*64 + 4096] = (float)(*nopen) / 31457280.0f;  // /(7680*4096)
}

extern "C" void kernel_launch(void* const* d_in, const int* in_sizes, int n_in,
                              void* d_out, int out_size, void* d_ws, size_t ws_size,
                              hipStream_t stream)
{
    const float* x  = (const float*)d_in[0];
    const float* Wi = (const float*)d_in[1];
    const float* bi = (const float*)d_in[2];
    const float* Wg = (const float*)d_in[3];
    const float* bg = (const float*)d_in[4];
    const float* Wd = (const float*)d_in[5];
    const float* Wo = (const float*)d_in[6];
    float* out = (float*)d_out;

    const size_t ACTS_BYTES = (size_t)4096 * NBF * 4;   // 10.5 MB
    bool use_ws = ws_size >= ACTS_BYTES + 64;

    float* acts0 = use_ws ? (float*)d_ws : nullptr;
    unsigned int* nopen = use_ws
        ? (unsigned int*)((char*)d_ws + ACTS_BYTES)
        : (unsigned int*)d_ws;

    hipMemsetAsync(nopen, 0, 4, stream);

    if (use_ws) {
        dim3 grid(4096 / BM, NBF / BN);
        input_gemm<<<grid, 256, 0, stream>>>(x, Wi, bi, acts0);
    }
    routenet_v3<<<4096 / NSB, 256, 0, stream>>>(
        acts0, x, Wi, bi, Wg, bg, Wd, Wo, out, nopen);
    finalize_prob<<<1, 1, 0, stream>>>(nopen, out);
}

// Round 4
// 372.067 us; speedup vs baseline: 2.6785x; 1.0336x over previous
//
#include <hip/hip_runtime.h>
#include <type_traits>

#define NIN 784
#define BANKS 64
#define NLAYER 15
#define FAN 8
#define DD 10
#define NBF (BANKS*DD)      // 640
#define NSW 4               // samples per sample-group (per wave)
#define NSB 8               // samples per block (2 groups x 4)

// ---------------- Kernel A: input GEMM ----------------
#define BM 128
#define BN 64
#define BK 16

__global__ __launch_bounds__(256)
void input_gemm(const float* __restrict__ x, const float* __restrict__ Wi,
                const float* __restrict__ bi, float* __restrict__ acts)
{
    __shared__ float As[BK][BM + 4];
    __shared__ float Bs[BK][BN + 4];
    const int tid = threadIdx.x;
    const int tx = tid & 15, ty = tid >> 4;
    const int m0 = blockIdx.x * BM;
    const int n0 = blockIdx.y * BN;

    float acc[8][4];
#pragma unroll
    for (int i = 0; i < 8; ++i)
#pragma unroll
        for (int j = 0; j < 4; ++j) acc[i][j] = 0.f;

    for (int kb = 0; kb < NIN / BK; ++kb) {
#pragma unroll
        for (int i = 0; i < 2; ++i) {
            int flat = tid + 256 * i;
            int m = flat >> 2, kq = flat & 3;
            float4 v = *(const float4*)(x + (m0 + m) * NIN + kb * BK + kq * 4);
            As[kq*4+0][m] = v.x; As[kq*4+1][m] = v.y;
            As[kq*4+2][m] = v.z; As[kq*4+3][m] = v.w;
        }
        {
            int n = tid >> 2, kq = tid & 3;
            float4 v = *(const float4*)(Wi + (n0 + n) * NIN + kb * BK + kq * 4);
            Bs[kq*4+0][n] = v.x; Bs[kq*4+1][n] = v.y;
            Bs[kq*4+2][n] = v.z; Bs[kq*4+3][n] = v.w;
        }
        __syncthreads();
#pragma unroll
        for (int k = 0; k < BK; ++k) {
            float4 a0 = *(const float4*)(&As[k][ty*8]);
            float4 a1 = *(const float4*)(&As[k][ty*8+4]);
            float4 bb = *(const float4*)(&Bs[k][tx*4]);
            float av[8] = {a0.x,a0.y,a0.z,a0.w,a1.x,a1.y,a1.z,a1.w};
            float bv[4] = {bb.x,bb.y,bb.z,bb.w};
#pragma unroll
            for (int i = 0; i < 8; ++i)
#pragma unroll
                for (int j = 0; j < 4; ++j)
                    acc[i][j] = fmaf(av[i], bv[j], acc[i][j]);
        }
        __syncthreads();
    }
    float4 bv = *(const float4*)(bi + n0 + tx*4);
#pragma unroll
    for (int i = 0; i < 8; ++i) {
        int row = m0 + ty*8 + i;
        float4 o;
        o.x = fmaxf(acc[i][0] + bv.x, 0.f);
        o.y = fmaxf(acc[i][1] + bv.y, 0.f);
        o.z = fmaxf(acc[i][2] + bv.z, 0.f);
        o.w = fmaxf(acc[i][3] + bv.w, 0.f);
        *(float4*)(acts + row * NBF + n0 + tx*4) = o;
    }
}

__device__ __forceinline__ float f4c_rt(const float4& v, int c) {
    return c == 0 ? v.x : (c == 1 ? v.y : (c == 2 ? v.z : v.w));
}

typedef const __attribute__((address_space(1))) void gas_void;
typedef __attribute__((address_space(3))) void las_void;

__device__ __forceinline__ void gll16(const void* g, void* l) {
    __builtin_amdgcn_global_load_lds((gas_void*)g, (las_void*)l, 16, 0, 0);
}

// ---------------- Kernel B: e-split waves, 2 blocks/CU ----------------
// Block = 4 waves: wave w -> g = w&1 (sample group of 4), h = w>>1 (e-half).
// lane = bank. Wd staged per-k (25 quads) + Wg (3 quads), double-buffered;
// bias double-buffered by layer parity. Wave h reads 13 of 25 Wd quads,
// computes e = 5h..5h+4, shuffles gated contributions by k. At layer end the
// two e-halves exchange their 5 new activation dims via a small LDS buffer
// (two phases). Counted vmcnt(7) + raw s_barrier keeps staging in flight.
__global__ __launch_bounds__(256, 2)
void routenet_v4(const float* __restrict__ acts0,
                 const float* __restrict__ x, const float* __restrict__ Wi,
                 const float* __restrict__ bi,
                 const float* __restrict__ Wg, const float* __restrict__ bg,
                 const float* __restrict__ Wd, const float* __restrict__ Wo,
                 float* __restrict__ out, unsigned int* __restrict__ nopen_g)
{
    __shared__ float4 wdbuf[2][25][64];    // 51200 B  [parity][quad][bank]
    __shared__ float4 wgchunk[2][3][64];   //  6144 B
    __shared__ float4 biasbuf[2][2][64];   //  4096 B  [layer parity][q][bank]
    __shared__ float  exch[2][NSW][5][64]; // 10240 B  [g][s][el][bank]

    const int tid  = threadIdx.x;
    const int lane = tid & 63;
    const int w    = tid >> 6;
    const int g    = w & 1;
    const int h    = w >> 1;
    const int b0   = blockIdx.x * NSB + g * NSW;

    float a[NSW][DD];

    if (acts0) {
#pragma unroll
        for (int s = 0; s < NSW; ++s) {
            const float2* p = (const float2*)(acts0 + (size_t)(b0 + s) * NBF + lane * DD);
#pragma unroll
            for (int d2 = 0; d2 < 5; ++d2) {
                float2 v = p[d2];
                a[s][d2*2]   = v.x;
                a[s][d2*2+1] = v.y;
            }
        }
    } else {
        for (int s = 0; s < NSW; ++s) {
            const float* xb = x + (size_t)(b0 + s) * NIN;
            for (int d = 0; d < DD; ++d) {
                int n = lane * DD + d;
                const float* wr = Wi + (size_t)n * NIN;
                float z = bi[n];
                for (int i = 0; i < NIN; ++i) z = fmaf(xb[i], wr[i], z);
                a[s][d] = fmaxf(z, 0.f);
            }
        }
    }

    float gsum[NSW];
#pragma unroll
    for (int s = 0; s < NSW; ++s) gsum[s] = 0.f;
    unsigned int nop = 0;

    // stage one k-chunk: 25 Wd quads + 3 Wg quads = 28 rows, 7 per wave
    auto stage_chunk = [&](int l, int k, int pdst) {
        const float* wd_base = Wd + (size_t)l * (BANKS*FAN*DD*DD)
                                  + (size_t)lane * (FAN*DD*DD) + k * (DD*DD);
        const float* wg_base = Wg + (size_t)l * (BANKS*FAN*DD)
                                  + lane * (FAN*DD) + ((10*k) >> 2) * 4;
#pragma unroll
        for (int j = 0; j < 7; ++j) {
            int r = w + 4 * j;
            if (r < 25) gll16(wd_base + r * 4, &wdbuf[pdst][r][0]);
            else        gll16(wg_base + (r - 25) * 4, &wgchunk[pdst][r - 25][0]);
        }
    };
    auto stage_bias = [&](int l) {
        if (w < 2)
            gll16(bg + (size_t)l * (BANKS*FAN) + lane * FAN + w * 4,
                  &biasbuf[l & 1][w][0]);
    };

    stage_chunk(0, 0, 0);
    stage_bias(0);
    asm volatile("s_waitcnt vmcnt(0)" ::: "memory");
    asm volatile("s_barrier" ::: "memory");

    for (int l = 0; l < NLAYER; ++l) {
        const int lp = l & 1;
        float acc[NSW][5];
#pragma unroll
        for (int s = 0; s < NSW; ++s)
#pragma unroll
            for (int el = 0; el < 5; ++el) acc[s][el] = 0.f;

        auto chunk_body = [&](auto Hc, int k, int p) {
            constexpr int H = Hc.value;
            // gate weights for this k (floats 10k..10k+9 inside 3 staged quads)
            float4 wgq[3];
#pragma unroll
            for (int q = 0; q < 3; ++q) wgq[q] = wgchunk[p][q][lane];
            const float bias = f4c_rt(biasbuf[lp][(k >> 2) & 1][lane], k & 3);
            float wgv[DD];
            if ((k & 1) == 0) {
#pragma unroll
                for (int d = 0; d < DD; ++d) wgv[d] = f4c_rt(wgq[d >> 2], d & 3);
            } else {
#pragma unroll
                for (int d = 0; d < DD; ++d) wgv[d] = f4c_rt(wgq[(d+2) >> 2], (d+2) & 3);
            }

            float gz[NSW];
#pragma unroll
            for (int s = 0; s < NSW; ++s) {
                float z = bias;
#pragma unroll
                for (int d = 0; d < DD; ++d) z = fmaf(a[s][d], wgv[d], z);
                float gate = fminf(fmaxf(z, 0.f), 1.f);
                if (H == 0) { gsum[s] += gate; nop += (z > 0.f) ? 1u : 0u; }
                gz[s] = gate;
            }

            // this half's 13 Wd quads (rows 12H .. 12H+12)
            float4 wv[13];
#pragma unroll
            for (int i = 0; i < 13; ++i) wv[i] = wdbuf[p][12*H + i][lane];

            const int src = (lane - k) & 63;
#pragma unroll
            for (int el = 0; el < 5; ++el) {
#pragma unroll
                for (int s = 0; s < NSW; ++s) {
                    float dot = 0.f;
#pragma unroll
                    for (int d = 0; d < DD; ++d) {
                        const int idx = (5*H + el) * 10 + d - 48*H;
                        dot = fmaf(a[s][d], f4c_rt(wv[idx >> 2], idx & 3), dot);
                    }
                    acc[s][el] += __shfl(gz[s] * dot, src, 64);
                }
            }
        };

#pragma unroll
        for (int c = 0; c < 8; ++c) {
            const int p = c & 1;
            if (c < 7) {
                stage_chunk(l, c + 1, p ^ 1);
                asm volatile("s_waitcnt vmcnt(7)" ::: "memory");
            } else if (l + 1 < NLAYER) {
                stage_chunk(l + 1, 0, p ^ 1);
                stage_bias(l + 1);
                asm volatile("s_waitcnt vmcnt(7)" ::: "memory");
            } else {
                asm volatile("s_waitcnt vmcnt(0)" ::: "memory");
            }
            asm volatile("s_barrier" ::: "memory");

            if (h == 0) chunk_body(std::integral_constant<int,0>{}, c, p);
            else        chunk_body(std::integral_constant<int,1>{}, c, p);

            if (c < 7) {
                asm volatile("s_waitcnt lgkmcnt(0)" ::: "memory");
                asm volatile("s_barrier" ::: "memory");
            }
        }

        // ReLU own half; phase A: h=1 publishes its half (d=5..9)
        if (h == 0) {
#pragma unroll
            for (int s = 0; s < NSW; ++s)
#pragma unroll
                for (int el = 0; el < 5; ++el)
                    a[s][el] = fmaxf(acc[s][el], 0.f);
        } else {
#pragma unroll
            for (int s = 0; s < NSW; ++s)
#pragma unroll
                for (int el = 0; el < 5; ++el) {
                    a[s][5 + el] = fmaxf(acc[s][el], 0.f);
                    exch[g][s][el][lane] = a[s][5 + el];
                }
        }
        // serves as chunk-7 trailing barrier AND phase-A publish (lgkm only:
        // next-layer staging stays in flight in vmcnt)
        asm volatile("s_waitcnt lgkmcnt(0)" ::: "memory");
        asm volatile("s_barrier" ::: "memory");

        if (h == 0) {
#pragma unroll
            for (int s = 0; s < NSW; ++s)
#pragma unroll
                for (int el = 0; el < 5; ++el)
                    a[s][5 + el] = exch[g][s][el][lane];
            if (l + 1 < NLAYER) {   // phase B: publish d=0..4
#pragma unroll
                for (int s = 0; s < NSW; ++s)
#pragma unroll
                    for (int el = 0; el < 5; ++el)
                        exch[g][s][el][lane] = a[s][el];
            }
        }
        if (l + 1 < NLAYER) {
            asm volatile("s_waitcnt lgkmcnt(0)" ::: "memory");
            asm volatile("s_barrier" ::: "memory");
            if (h == 1) {
#pragma unroll
                for (int s = 0; s < NSW; ++s)
#pragma unroll
                    for (int el = 0; el < 5; ++el)
                        a[s][el] = exch[g][s][el][lane];
            }
        }
    }

    // epilogue (h=0 waves have full a)
    if (h == 0) {
        float wo[DD];
        const float2* p = (const float2*)(Wo + lane * DD);
#pragma unroll
        for (int d2 = 0; d2 < 5; ++d2) {
            float2 v = p[d2];
            wo[d2*2] = v.x; wo[d2*2+1] = v.y;
        }
#pragma unroll
        for (int s = 0; s < NSW; ++s) {
            float v = 0.f;
#pragma unroll
            for (int d = 0; d < DD; ++d) v = fmaf(a[s][d], wo[d], v);
            out[(size_t)(b0 + s) * BANKS + lane] = fmaxf(v, 0.f);
        }

#pragma unroll
        for (int s = 0; s < NSW; ++s) {
            float v = gsum[s];
#pragma unroll
            for (int off = 32; off; off >>= 1) v += __shfl_xor(v, off, 64);
            if (lane == 0)
                out[(size_t)4096 * BANKS + b0 + s] = v * (1.0f / 7680.0f);
        }
        {
            unsigned int v = nop;
#pragma unroll
            for (int off = 32; off; off >>= 1) v += __shfl_xor(v, off, 64);
            if (lane == 0) atomicAdd(nopen_g, v);
        }
    }
}

// ---------------- Kernel C: finalize scalar ----------------
__global__ void finalize_prob(const unsigned int* __restrict__ nopen,
                              float* __restrict__ out)
{
    out[4096*64 + 4096] = (float)(*nopen) / 31457280.0f;  // /(7680*4096)
}

extern "C" void kernel_launch(void* const* d_in, const int* in_sizes, int n_in,
                              void* d_out, int out_size, void* d_ws, size_t ws_size,
                              hipStream_t stream)
{
    const float* x  = (const float*)d_in[0];
    const float* Wi = (const float*)d_in[1];
    const float* bi = (const float*)d_in[2];
    const float* Wg = (const float*)d_in[3];
    const float* bg = (const float*)d_in[4];
    const float* Wd = (const float*)d_in[5];
    const float* Wo = (const float*)d_in[6];
    float* out = (float*)d_out;

    const size_t ACTS_BYTES = (size_t)4096 * NBF * 4;   // 10.5 MB
    bool use_ws = ws_size >= ACTS_BYTES + 64;

    float* acts0 = use_ws ? (float*)d_ws : nullptr;
    unsigned int* nopen = use_ws
        ? (unsigned int*)((char*)d_ws + ACTS_BYTES)
        : (unsigned int*)d_ws;

    hipMemsetAsync(nopen, 0, 4, stream);

    if (use_ws) {
        dim3 grid(4096 / BM, NBF / BN);
        input_gemm<<<grid, 256, 0, stream>>>(x, Wi, bi, acts0);
    }
    routenet_v4<<<4096 / NSB, 256, 0, stream>>>(
        acts0, x, Wi, bi, Wg, bg, Wd, Wo, out, nopen);
    finalize_prob<<<1, 1, 0, stream>>>(nopen, out);
}

// Round 5
// 302.053 us; speedup vs baseline: 3.2994x; 1.2318x over previous
//
#include <hip/hip_runtime.h>
#include <type_traits>

#define NIN 784
#define BANKS 64
#define NLAYER 15
#define FAN 8
#define DD 10
#define NBF 640             // features per sample per layer
#define NSW 4               // samples per sample-group (per wave)
#define NSB 8               // samples per block (2 groups x 4)

// ---------------- Kernel A: input GEMM ----------------
#define BM 128
#define BN 64
#define BK 16

__global__ __launch_bounds__(256)
void input_gemm(const float* __restrict__ x, const float* __restrict__ Wi,
                const float* __restrict__ bi, float* __restrict__ acts)
{
    __shared__ float As[BK][BM + 4];
    __shared__ float Bs[BK][BN + 4];
    const int tid = threadIdx.x;
    const int tx = tid & 15, ty = tid >> 4;
    const int m0 = blockIdx.x * BM;
    const int n0 = blockIdx.y * BN;

    float acc[8][4];
#pragma unroll
    for (int i = 0; i < 8; ++i)
#pragma unroll
        for (int j = 0; j < 4; ++j) acc[i][j] = 0.f;

    for (int kb = 0; kb < NIN / BK; ++kb) {
#pragma unroll
        for (int i = 0; i < 2; ++i) {
            int flat = tid + 256 * i;
            int m = flat >> 2, kq = flat & 3;
            float4 v = *(const float4*)(x + (m0 + m) * NIN + kb * BK + kq * 4);
            As[kq*4+0][m] = v.x; As[kq*4+1][m] = v.y;
            As[kq*4+2][m] = v.z; As[kq*4+3][m] = v.w;
        }
        {
            int n = tid >> 2, kq = tid & 3;
            float4 v = *(const float4*)(Wi + (n0 + n) * NIN + kb * BK + kq * 4);
            Bs[kq*4+0][n] = v.x; Bs[kq*4+1][n] = v.y;
            Bs[kq*4+2][n] = v.z; Bs[kq*4+3][n] = v.w;
        }
        __syncthreads();
#pragma unroll
        for (int k = 0; k < BK; ++k) {
            float4 a0 = *(const float4*)(&As[k][ty*8]);
            float4 a1 = *(const float4*)(&As[k][ty*8+4]);
            float4 bb = *(const float4*)(&Bs[k][tx*4]);
            float av[8] = {a0.x,a0.y,a0.z,a0.w,a1.x,a1.y,a1.z,a1.w};
            float bv[4] = {bb.x,bb.y,bb.z,bb.w};
#pragma unroll
            for (int i = 0; i < 8; ++i)
#pragma unroll
                for (int j = 0; j < 4; ++j)
                    acc[i][j] = fmaf(av[i], bv[j], acc[i][j]);
        }
        __syncthreads();
    }
    float4 bv = *(const float4*)(bi + n0 + tx*4);
#pragma unroll
    for (int i = 0; i < 8; ++i) {
        int row = m0 + ty*8 + i;
        float4 o;
        o.x = fmaxf(acc[i][0] + bv.x, 0.f);
        o.y = fmaxf(acc[i][1] + bv.y, 0.f);
        o.z = fmaxf(acc[i][2] + bv.z, 0.f);
        o.w = fmaxf(acc[i][3] + bv.w, 0.f);
        *(float4*)(acts + row * NBF + n0 + tx*4) = o;
    }
}

__device__ __forceinline__ float f4c_rt(const float4& v, int c) {
    return c == 0 ? v.x : (c == 1 ? v.y : (c == 2 ? v.z : v.w));
}

typedef const __attribute__((address_space(1))) void gas_void;
typedef __attribute__((address_space(3))) void las_void;

__device__ __forceinline__ void gll16(const void* g, void* l) {
    __builtin_amdgcn_global_load_lds((gas_void*)g, (las_void*)l, 16, 0, 0);
}

// ---------------- Kernel T: weight pre-transpose ----------------
// chunk_t[l][k][r=0..27][bank] float4:
//   r<25 : Wd[l][bank][k] floats 4r..4r+3
//   r>=25: Wg[l][bank][k] floats 4(r-25)..+3 (zero-padded past 10)
// bias_t[l][q=0..1][bank] float4 = bg[l][bank][4q..4q+3]
#define NCH (NLAYER*FAN*28*64)   // 215040
#define NBI (NLAYER*2*64)        // 1920

__global__ __launch_bounds__(256)
void transpose_weights(const float* __restrict__ Wg, const float* __restrict__ bg,
                       const float* __restrict__ Wd,
                       float4* __restrict__ chunk_t, float4* __restrict__ bias_t)
{
    int tid = blockIdx.x * 256 + threadIdx.x;
    if (tid < NCH) {
        int b = tid & 63;
        int rk = tid >> 6;
        int r = rk % 28;
        int lk = rk / 28;           // l*8+k
        int k = lk & 7;
        int l = lk >> 3;
        float4 v;
        if (r < 25) {
            v = ((const float4*)Wd)[(((size_t)(l*64+b)*8 + k)*25) + r];
        } else {
            int q = r - 25;
            size_t base = ((size_t)(l*64+b)*8 + k)*10 + 4*q;
            float t[4];
#pragma unroll
            for (int c = 0; c < 4; ++c)
                t[c] = (4*q + c < 10) ? Wg[base + c] : 0.f;
            v = make_float4(t[0], t[1], t[2], t[3]);
        }
        chunk_t[tid] = v;
    } else if (tid < NCH + NBI) {
        int t2 = tid - NCH;
        int b = t2 & 63;
        int q = (t2 >> 6) & 1;
        int l = t2 >> 7;
        bias_t[t2] = ((const float4*)bg)[(size_t)(l*64+b)*2 + q];
    }
}

// ---------------- Kernel B: e-split waves, coalesced LDS staging ----------------
// Block = 4 waves: wave w -> g = w&1 (sample group), h = w>>1 (e-half).
// lane = bank. Per-k chunk (28 rows of [64]float4) staged double-buffered via
// coalesced global_load_lds from pre-transposed chunk_t (CT=true) or scattered
// from original layout (CT=false fallback). Counted vmcnt (7 mid-layer, 8 at
// layer boundary) + raw s_barrier keeps staging in flight.
template<bool CT>
__global__ __launch_bounds__(256, 2)
void routenet_v5(const float* __restrict__ acts0,
                 const float* __restrict__ x, const float* __restrict__ Wi,
                 const float* __restrict__ bi,
                 const float* __restrict__ Wg, const float* __restrict__ bg,
                 const float* __restrict__ Wd, const float* __restrict__ Wo,
                 const float4* __restrict__ chunk_t, const float4* __restrict__ bias_t,
                 float* __restrict__ out, unsigned int* __restrict__ nopen_g)
{
    __shared__ float4 wdstage[2][28][64];  // 57344 B (rows 0-24 Wd, 25-27 Wg)
    __shared__ float4 biasbuf[2][2][64];   //  4096 B [layer parity][q][bank]
    __shared__ float  exch[2][NSW][5][64]; // 10240 B [g][s][el][bank]

    const int tid  = threadIdx.x;
    const int lane = tid & 63;
    const int w    = tid >> 6;
    const int g    = w & 1;
    const int h    = w >> 1;
    const int b0   = blockIdx.x * NSB + g * NSW;

    float a[NSW][DD];

    if (acts0) {
#pragma unroll
        for (int s = 0; s < NSW; ++s) {
            const float2* p = (const float2*)(acts0 + (size_t)(b0 + s) * NBF + lane * DD);
#pragma unroll
            for (int d2 = 0; d2 < 5; ++d2) {
                float2 v = p[d2];
                a[s][d2*2]   = v.x;
                a[s][d2*2+1] = v.y;
            }
        }
    } else {
        for (int s = 0; s < NSW; ++s) {
            const float* xb = x + (size_t)(b0 + s) * NIN;
            for (int d = 0; d < DD; ++d) {
                int n = lane * DD + d;
                const float* wr = Wi + (size_t)n * NIN;
                float z = bi[n];
                for (int i = 0; i < NIN; ++i) z = fmaf(xb[i], wr[i], z);
                a[s][d] = fmaxf(z, 0.f);
            }
        }
    }

    float gsum[NSW];
#pragma unroll
    for (int s = 0; s < NSW; ++s) gsum[s] = 0.f;
    unsigned int nop = 0;

    // --- staging: 28 rows per chunk, 7 per wave; bias 1 per thread (dup) ---
    auto stage_chunk = [&](int l, int k, int pdst) {
        if constexpr (CT) {
            const float4* base = chunk_t + (size_t)(l*8 + k) * 28 * 64;
#pragma unroll
            for (int j = 0; j < 7; ++j) {
                int r = w + 4 * j;
                gll16(base + r*64 + lane, &wdstage[pdst][r][0]);
            }
        } else {
            const float* wd_base = Wd + (size_t)l * (BANKS*FAN*DD*DD)
                                      + (size_t)lane * (FAN*DD*DD) + k * (DD*DD);
            const float* wg_base = Wg + (size_t)l * (BANKS*FAN*DD)
                                      + lane * (FAN*DD) + ((10*k) >> 2) * 4;
#pragma unroll
            for (int j = 0; j < 7; ++j) {
                int r = w + 4 * j;
                if (r < 25) gll16(wd_base + r * 4, &wdstage[pdst][r][0]);
                else        gll16(wg_base + (r - 25) * 4, &wdstage[pdst][r][0]);
            }
        }
    };
    auto stage_bias = [&](int l) {
        int q = w & 1;   // waves 0,2 -> q0; 1,3 -> q1 (duplicate, idempotent)
        if constexpr (CT) {
            gll16(bias_t + (size_t)(l*2 + q)*64 + lane, &biasbuf[l & 1][q][0]);
        } else {
            gll16(bg + (size_t)l * (BANKS*FAN) + lane * FAN + q * 4,
                  &biasbuf[l & 1][q][0]);
        }
    };

    stage_chunk(0, 0, 0);
    stage_bias(0);
    asm volatile("s_waitcnt vmcnt(0)" ::: "memory");
    asm volatile("s_barrier" ::: "memory");

    for (int l = 0; l < NLAYER; ++l) {
        const int lp = l & 1;
        float acc[NSW][5];
#pragma unroll
        for (int s = 0; s < NSW; ++s)
#pragma unroll
            for (int el = 0; el < 5; ++el) acc[s][el] = 0.f;

        auto chunk_body = [&](auto Hc, int k, int p) {
            constexpr int H = Hc.value;
            float4 wgq[3];
#pragma unroll
            for (int q = 0; q < 3; ++q) wgq[q] = wdstage[p][25 + q][lane];
            const float bias = f4c_rt(biasbuf[lp][(k >> 2) & 1][lane], k & 3);
            float wgv[DD];
            if constexpr (CT) {
#pragma unroll
                for (int d = 0; d < DD; ++d) wgv[d] = f4c_rt(wgq[d >> 2], d & 3);
            } else {
                if ((k & 1) == 0) {
#pragma unroll
                    for (int d = 0; d < DD; ++d) wgv[d] = f4c_rt(wgq[d >> 2], d & 3);
                } else {
#pragma unroll
                    for (int d = 0; d < DD; ++d) wgv[d] = f4c_rt(wgq[(d+2) >> 2], (d+2) & 3);
                }
            }

            float gz[NSW];
#pragma unroll
            for (int s = 0; s < NSW; ++s) {
                float z = bias;
#pragma unroll
                for (int d = 0; d < DD; ++d) z = fmaf(a[s][d], wgv[d], z);
                float gate = fminf(fmaxf(z, 0.f), 1.f);
                if (H == 0) { gsum[s] += gate; nop += (z > 0.f) ? 1u : 0u; }
                gz[s] = gate;
            }

            float4 wv[13];
#pragma unroll
            for (int i = 0; i < 13; ++i) wv[i] = wdstage[p][12*H + i][lane];

            const int src = (lane - k) & 63;
#pragma unroll
            for (int el = 0; el < 5; ++el) {
#pragma unroll
                for (int s = 0; s < NSW; ++s) {
                    float dot = 0.f;
#pragma unroll
                    for (int d = 0; d < DD; ++d) {
                        const int idx = (5*H + el) * 10 + d - 48*H;
                        dot = fmaf(a[s][d], f4c_rt(wv[idx >> 2], idx & 3), dot);
                    }
                    acc[s][el] += __shfl(gz[s] * dot, src, 64);
                }
            }
        };

#pragma unroll
        for (int c = 0; c < 8; ++c) {
            const int p = c & 1;
            if (c < 7) {
                stage_chunk(l, c + 1, p ^ 1);
                asm volatile("s_waitcnt vmcnt(7)" ::: "memory");
            } else if (l + 1 < NLAYER) {
                stage_chunk(l + 1, 0, p ^ 1);
                stage_bias(l + 1);
                asm volatile("s_waitcnt vmcnt(8)" ::: "memory");
            } else {
                asm volatile("s_waitcnt vmcnt(0)" ::: "memory");
            }
            asm volatile("s_barrier" ::: "memory");

            if (h == 0) chunk_body(std::integral_constant<int,0>{}, c, p);
            else        chunk_body(std::integral_constant<int,1>{}, c, p);

            if (c < 7) {
                asm volatile("s_waitcnt lgkmcnt(0)" ::: "memory");
                asm volatile("s_barrier" ::: "memory");
            }
        }

        // ReLU own half; phase A: h=1 publishes its half (d=5..9)
        if (h == 0) {
#pragma unroll
            for (int s = 0; s < NSW; ++s)
#pragma unroll
                for (int el = 0; el < 5; ++el)
                    a[s][el] = fmaxf(acc[s][el], 0.f);
        } else {
#pragma unroll
            for (int s = 0; s < NSW; ++s)
#pragma unroll
                for (int el = 0; el < 5; ++el) {
                    a[s][5 + el] = fmaxf(acc[s][el], 0.f);
                    exch[g][s][el][lane] = a[s][5 + el];
                }
        }
        asm volatile("s_waitcnt lgkmcnt(0)" ::: "memory");
        asm volatile("s_barrier" ::: "memory");

        if (h == 0) {
#pragma unroll
            for (int s = 0; s < NSW; ++s)
#pragma unroll
                for (int el = 0; el < 5; ++el)
                    a[s][5 + el] = exch[g][s][el][lane];
            if (l + 1 < NLAYER) {   // phase B: publish d=0..4
#pragma unroll
                for (int s = 0; s < NSW; ++s)
#pragma unroll
                    for (int el = 0; el < 5; ++el)
                        exch[g][s][el][lane] = a[s][el];
            }
        }
        if (l + 1 < NLAYER) {
            asm volatile("s_waitcnt lgkmcnt(0)" ::: "memory");
            asm volatile("s_barrier" ::: "memory");
            if (h == 1) {
#pragma unroll
                for (int s = 0; s < NSW; ++s)
#pragma unroll
                    for (int el = 0; el < 5; ++el)
                        a[s][el] = exch[g][s][el][lane];
            }
        }
    }

    // epilogue (h=0 waves have full a)
    if (h == 0) {
        float wo[DD];
        const float2* p = (const float2*)(Wo + lane * DD);
#pragma unroll
        for (int d2 = 0; d2 < 5; ++d2) {
            float2 v = p[d2];
            wo[d2*2] = v.x; wo[d2*2+1] = v.y;
        }
#pragma unroll
        for (int s = 0; s < NSW; ++s) {
            float v = 0.f;
#pragma unroll
            for (int d = 0; d < DD; ++d) v = fmaf(a[s][d], wo[d], v);
            out[(size_t)(b0 + s) * BANKS + lane] = fmaxf(v, 0.f);
        }

#pragma unroll
        for (int s = 0; s < NSW; ++s) {
            float v = gsum[s];
#pragma unroll
            for (int off = 32; off; off >>= 1) v += __shfl_xor(v, off, 64);
            if (lane == 0)
                out[(size_t)4096 * BANKS + b0 + s] = v * (1.0f / 7680.0f);
        }
        {
            unsigned int v = nop;
#pragma unroll
            for (int off = 32; off; off >>= 1) v += __shfl_xor(v, off, 64);
            if (lane == 0) atomicAdd(nopen_g, v);
        }
    }
}

// ---------------- Kernel C: finalize scalar ----------------
__global__ void finalize_prob(const unsigned int* __restrict__ nopen,
                              float* __restrict__ out)
{
    out[4096*64 + 4096] = (float)(*nopen) / 31457280.0f;  // /(7680*4096)
}

extern "C" void kernel_launch(void* const* d_in, const int* in_sizes, int n_in,
                              void* d_out, int out_size, void* d_ws, size_t ws_size,
                              hipStream_t stream)
{
    const float* x  = (const float*)d_in[0];
    const float* Wi = (const float*)d_in[1];
    const float* bi = (const float*)d_in[2];
    const float* Wg = (const float*)d_in[3];
    const float* bg = (const float*)d_in[4];
    const float* Wd = (const float*)d_in[5];
    const float* Wo = (const float*)d_in[6];
    float* out = (float*)d_out;

    const size_t ACTS_BYTES  = (size_t)4096 * NBF * 4;          // 10485760
    const size_t CHUNK_BYTES = (size_t)NCH * 16;                //  3440640
    const size_t BIAS_BYTES  = (size_t)NBI * 16;                //    30720
    const size_t FULL_BYTES  = ACTS_BYTES + CHUNK_BYTES + BIAS_BYTES + 64;

    bool full    = ws_size >= FULL_BYTES;
    bool actonly = !full && ws_size >= ACTS_BYTES + 64;

    float* acts0 = (full || actonly) ? (float*)d_ws : nullptr;
    float4* chunk_t = full ? (float4*)((char*)d_ws + ACTS_BYTES) : nullptr;
    float4* bias_t  = full ? (float4*)((char*)d_ws + ACTS_BYTES + CHUNK_BYTES) : nullptr;
    unsigned int* nopen = full
        ? (unsigned int*)((char*)d_ws + ACTS_BYTES + CHUNK_BYTES + BIAS_BYTES)
        : (actonly ? (unsigned int*)((char*)d_ws + ACTS_BYTES)
                   : (unsigned int*)d_ws);

    hipMemsetAsync(nopen, 0, 4, stream);

    if (acts0) {
        dim3 grid(4096 / BM, NBF / BN);
        input_gemm<<<grid, 256, 0, stream>>>(x, Wi, bi, acts0);
    }
    if (full) {
        transpose_weights<<<(NCH + NBI + 255) / 256, 256, 0, stream>>>(
            Wg, bg, Wd, chunk_t, bias_t);
        routenet_v5<true><<<4096 / NSB, 256, 0, stream>>>(
            acts0, x, Wi, bi, Wg, bg, Wd, Wo, chunk_t, bias_t, out, nopen);
    } else {
        routenet_v5<false><<<4096 / NSB, 256, 0, stream>>>(
            acts0, x, Wi, bi, Wg, bg, Wd, Wo, nullptr, nullptr, out, nopen);
    }
    finalize_prob<<<1, 1, 0, stream>>>(nopen, out);
}